// Round 5
// baseline (433.376 us; speedup 1.0000x reference)
//
#include <hip/hip_runtime.h>

// GraphSAGE link predictor. f16 intermediates, fused node GEMMs, f16-MFMA edge MLP.
// Pipeline:
//  kA: x16 = f16(x) + deg hist            (fused)
//  scan -> row ; bucket -> srcs (CSR)
//  agg16 = f16(segsum(x16[src]))          (gather, f32 accum)
//  k_h1_fused: h1 = (agg*inv)@Wl1 + x@Wr1 + bl1 (f16 out) ; g16 = h1@Wl2 (LDS-fused)
//  agg16 = f16(segsum(g16[src]))          (gather)
//  k_h2: h2 = h1@Wr2 + agg*inv + bl2      (f16 out)
//  out[e] = relu((h2[s]*h2[d])@W1+b1)@W2 + b2   (MFMA f16, original edge order)

typedef _Float16 f16x8 __attribute__((ext_vector_type(8)));
typedef float f32x4 __attribute__((ext_vector_type(4)));

union H4 { _Float16 h[4]; uint2 u; };

__device__ inline float4 load4f(const float* p) { return *(const float4*)p; }
__device__ inline float4 load4f(const _Float16* p) {
  H4 h; h.u = *(const uint2*)p;
  return make_float4((float)h.h[0], (float)h.h[1], (float)h.h[2], (float)h.h[3]);
}
__device__ inline uint2 pack4(float4 v) {
  H4 p;
  p.h[0] = (_Float16)v.x; p.h[1] = (_Float16)v.y;
  p.h[2] = (_Float16)v.z; p.h[3] = (_Float16)v.w;
  return p.u;
}

// ---------------- kA: f32->f16 convert + deg histogram ----------------
__global__ void kA_convert_hist(const float* __restrict__ x, _Float16* __restrict__ x16,
                                const int* __restrict__ dst, int* __restrict__ deg,
                                int n4, int E) {
  int t = blockIdx.x * blockDim.x + threadIdx.x;
  if (t < n4) {
    float4 v = ((const float4*)x)[t];
    ((uint2*)x16)[t] = pack4(v);
  }
  if (t < E) atomicAdd(&deg[dst[t]], 1);
}

// ---------------- scans ----------------
__global__ void k_scan1(const int* __restrict__ deg, int* __restrict__ ex,
                        int* __restrict__ bsum, int N) {
  __shared__ int sm[256];
  int t = threadIdx.x, i = blockIdx.x * 256 + t;
  int v = (i < N) ? deg[i] : 0;
  sm[t] = v;
  __syncthreads();
  for (int s = 1; s < 256; s <<= 1) {
    int a = (t >= s) ? sm[t - s] : 0;
    __syncthreads();
    sm[t] += a;
    __syncthreads();
  }
  if (i < N) ex[i] = sm[t] - v;
  if (t == 255) bsum[blockIdx.x] = sm[255];
}

__global__ void k_scan2(int* __restrict__ bsum, int nb) {
  __shared__ int sm[1024];
  int t = threadIdx.x;
  int v = (t < nb) ? bsum[t] : 0;
  sm[t] = v;
  __syncthreads();
  for (int s = 1; s < 1024; s <<= 1) {
    int a = (t >= s) ? sm[t - s] : 0;
    __syncthreads();
    sm[t] += a;
    __syncthreads();
  }
  if (t < nb) bsum[t] = sm[t] - v;
}

__global__ void k_scan3(const int* __restrict__ bsum, int* __restrict__ row,
                        int* __restrict__ cursor, int N, int E) {
  int i = blockIdx.x * blockDim.x + threadIdx.x;
  if (i < N) {
    int v = cursor[i] + bsum[i >> 8];
    row[i] = v;
    cursor[i] = v;
  }
  if (i == 0) row[N] = E;
}

__global__ void k_bucket(const int* __restrict__ src, const int* __restrict__ dst,
                         int* __restrict__ cursor, int* __restrict__ srcs, int E) {
  int e = blockIdx.x * blockDim.x + threadIdx.x;
  if (e < E) {
    int pos = atomicAdd(&cursor[dst[e]], 1);
    __builtin_nontemporal_store(src[e], &srcs[pos]);
  }
}

// ---------------- aggregation: 16 lanes/row, unroll 4, f16 out ----------------
__global__ __launch_bounds__(256) void k_gather16(
    const _Float16* __restrict__ feat, const int* __restrict__ row,
    const int* __restrict__ srcs, _Float16* __restrict__ agg, int N) {
  int tid = blockIdx.x * blockDim.x + threadIdx.x;
  int node = tid >> 4, slot = tid & 15;
  if (node >= N) return;
  int beg = row[node], end = row[node + 1];
  float4 acc = make_float4(0.f, 0.f, 0.f, 0.f);
  int k = beg;
  for (; k + 3 < end; k += 4) {
    int s0 = srcs[k], s1 = srcs[k + 1], s2 = srcs[k + 2], s3 = srcs[k + 3];
    H4 a, b, c, d;
    a.u = *(const uint2*)(feat + (size_t)s0 * 64 + slot * 4);
    b.u = *(const uint2*)(feat + (size_t)s1 * 64 + slot * 4);
    c.u = *(const uint2*)(feat + (size_t)s2 * 64 + slot * 4);
    d.u = *(const uint2*)(feat + (size_t)s3 * 64 + slot * 4);
    acc.x += ((float)a.h[0] + (float)b.h[0]) + ((float)c.h[0] + (float)d.h[0]);
    acc.y += ((float)a.h[1] + (float)b.h[1]) + ((float)c.h[1] + (float)d.h[1]);
    acc.z += ((float)a.h[2] + (float)b.h[2]) + ((float)c.h[2] + (float)d.h[2]);
    acc.w += ((float)a.h[3] + (float)b.h[3]) + ((float)c.h[3] + (float)d.h[3]);
  }
  for (; k < end; k++) {
    int s0 = srcs[k];
    H4 a; a.u = *(const uint2*)(feat + (size_t)s0 * 64 + slot * 4);
    acc.x += (float)a.h[0]; acc.y += (float)a.h[1];
    acc.z += (float)a.h[2]; acc.w += (float)a.h[3];
  }
  *(uint2*)(agg + (size_t)node * 64 + slot * 4) = pack4(acc);
}

// ---------------- fused h1 + g: 64-node tile ----------------
// h1 = (agg16*inv)@Wl1 + x@Wr1 + bl1  -> h1o (f16) and LDS h1T
// g  = h1@Wl2                          -> g16 (f16)
__global__ __launch_bounds__(256) void k_h1_fused(
    const _Float16* __restrict__ agg16, const float* __restrict__ x,
    const int* __restrict__ deg,
    const float* __restrict__ Wl1, const float* __restrict__ Wr1,
    const float* __restrict__ bl1, const float* __restrict__ Wl2,
    _Float16* __restrict__ h1o, _Float16* __restrict__ g16, int N) {
  __shared__ __align__(16) char smem[38912];
  float (*At)[64]  = (float(*)[64])smem;            // 16x64   (phase 1/2)
  float (*Wt)[128] = (float(*)[128])(smem + 4096);  // 16x128  (phase 1/2)
  float (*h1T)[68] = (float(*)[68])smem;            // 128x68  (g phase)
  float (*Wt2)[64] = (float(*)[64])(smem + 34816);  // 16x64   (g phase)

  const int t = threadIdx.x;
  const int jt = t & 31, nt = t >> 5;
  const int j0 = jt * 4, n0 = nt * 8;
  const int nbase = blockIdx.x * 64;

  float4 acc[8];
#pragma unroll
  for (int r = 0; r < 8; r++) acc[r] = make_float4(0.f, 0.f, 0.f, 0.f);

  auto phase = [&](auto S, const float* __restrict__ Wm) {
    for (int kb = 0; kb < 64; kb += 16) {
      {
        int n = t >> 2, kq = t & 3;
        int node = nbase + n;
        int nclamp = node < N ? node : N - 1;
        float4 v = load4f(S + (size_t)nclamp * 64 + kb + kq * 4);
        At[kq * 4 + 0][n] = v.x;
        At[kq * 4 + 1][n] = v.y;
        At[kq * 4 + 2][n] = v.z;
        At[kq * 4 + 3][n] = v.w;
      }
      {
        const float* ws = Wm + (size_t)kb * 128;
        float* wd = &Wt[0][0];
        *(float4*)(wd + t * 4) = *(const float4*)(ws + t * 4);
        *(float4*)(wd + (t + 256) * 4) = *(const float4*)(ws + (t + 256) * 4);
      }
      __syncthreads();
#pragma unroll
      for (int kk = 0; kk < 16; kk++) {
        float4 w = *(const float4*)&Wt[kk][j0];
        float4 a0 = *(const float4*)&At[kk][n0];
        float4 a1 = *(const float4*)&At[kk][n0 + 4];
        float av[8] = {a0.x, a0.y, a0.z, a0.w, a1.x, a1.y, a1.z, a1.w};
#pragma unroll
        for (int r = 0; r < 8; r++) {
          acc[r].x += av[r] * w.x;
          acc[r].y += av[r] * w.y;
          acc[r].z += av[r] * w.z;
          acc[r].w += av[r] * w.w;
        }
      }
      __syncthreads();
    }
  };

  phase(agg16, Wl1);
#pragma unroll
  for (int r = 0; r < 8; r++) {
    int node = nbase + n0 + r;
    float inv = (node < N) ? 1.0f / fmaxf((float)deg[node], 1.0f) : 1.f;
    acc[r].x *= inv; acc[r].y *= inv; acc[r].z *= inv; acc[r].w *= inv;
  }
  phase(x, Wr1);
  {
    float4 b = *(const float4*)&bl1[j0];
#pragma unroll
    for (int r = 0; r < 8; r++) {
      acc[r].x += b.x; acc[r].y += b.y; acc[r].z += b.z; acc[r].w += b.w;
    }
  }

  // write h1 (f16) + stage h1T for g phase
#pragma unroll
  for (int r = 0; r < 8; r++) {
    int node = nbase + n0 + r;
    if (node < N) *(uint2*)(h1o + (size_t)node * 128 + j0) = pack4(acc[r]);
    h1T[j0 + 0][n0 + r] = acc[r].x;
    h1T[j0 + 1][n0 + r] = acc[r].y;
    h1T[j0 + 2][n0 + r] = acc[r].z;
    h1T[j0 + 3][n0 + r] = acc[r].w;
  }
  __syncthreads();

  // g = h1 @ Wl2  (K=128, J=64)
  const int jt2 = t & 15, nt2 = t >> 4;
  const int j02 = jt2 * 4, n02 = nt2 * 4;
  float4 acc2[4];
#pragma unroll
  for (int i = 0; i < 4; i++) acc2[i] = make_float4(0.f, 0.f, 0.f, 0.f);

  for (int kb = 0; kb < 128; kb += 16) {
    *(float4*)(&Wt2[0][0] + t * 4) = *(const float4*)(Wl2 + (size_t)kb * 64 + t * 4);
    __syncthreads();
#pragma unroll
    for (int kk = 0; kk < 16; kk++) {
      float4 w = *(const float4*)&Wt2[kk][j02];
      float4 a = *(const float4*)&h1T[kb + kk][n02];
      acc2[0].x += a.x * w.x; acc2[0].y += a.x * w.y; acc2[0].z += a.x * w.z; acc2[0].w += a.x * w.w;
      acc2[1].x += a.y * w.x; acc2[1].y += a.y * w.y; acc2[1].z += a.y * w.z; acc2[1].w += a.y * w.w;
      acc2[2].x += a.z * w.x; acc2[2].y += a.z * w.y; acc2[2].z += a.z * w.z; acc2[2].w += a.z * w.w;
      acc2[3].x += a.w * w.x; acc2[3].y += a.w * w.y; acc2[3].z += a.w * w.z; acc2[3].w += a.w * w.w;
    }
    __syncthreads();
  }
#pragma unroll
  for (int i = 0; i < 4; i++) {
    int node = nbase + n02 + i;
    if (node < N) *(uint2*)(g16 + (size_t)node * 64 + j02) = pack4(acc2[i]);
  }
}

// ---------------- h2 = h1@Wr2 + agg16*inv + bl2 (f16 out) ----------------
__global__ __launch_bounds__(256) void k_h2(
    const _Float16* __restrict__ h1, const _Float16* __restrict__ agg16,
    const int* __restrict__ deg, const float* __restrict__ Wr2,
    const float* __restrict__ bl2, _Float16* __restrict__ h2, int N) {
  __shared__ float At[16][64];
  __shared__ float Wt[16][64];
  const int t = threadIdx.x;
  const int jt = t & 15, nt = t >> 4;
  const int j0 = jt * 4, n0 = nt * 4;
  const int nbase = blockIdx.x * 64;

  float4 acc[4];
#pragma unroll
  for (int i = 0; i < 4; i++) acc[i] = make_float4(0.f, 0.f, 0.f, 0.f);

  for (int kb = 0; kb < 128; kb += 16) {
    {
      int n = t >> 2, kq = t & 3;
      int node = nbase + n;
      int nclamp = node < N ? node : N - 1;
      float4 v = load4f(h1 + (size_t)nclamp * 128 + kb + kq * 4);
      At[kq * 4 + 0][n] = v.x;
      At[kq * 4 + 1][n] = v.y;
      At[kq * 4 + 2][n] = v.z;
      At[kq * 4 + 3][n] = v.w;
    }
    *(float4*)(&Wt[0][0] + t * 4) = *(const float4*)(Wr2 + (size_t)kb * 64 + t * 4);
    __syncthreads();
#pragma unroll
    for (int kk = 0; kk < 16; kk++) {
      float4 w = *(const float4*)&Wt[kk][j0];
      float4 a = *(const float4*)&At[kk][n0];
      acc[0].x += a.x * w.x; acc[0].y += a.x * w.y; acc[0].z += a.x * w.z; acc[0].w += a.x * w.w;
      acc[1].x += a.y * w.x; acc[1].y += a.y * w.y; acc[1].z += a.y * w.z; acc[1].w += a.y * w.w;
      acc[2].x += a.z * w.x; acc[2].y += a.z * w.y; acc[2].z += a.z * w.z; acc[2].w += a.z * w.w;
      acc[3].x += a.w * w.x; acc[3].y += a.w * w.y; acc[3].z += a.w * w.z; acc[3].w += a.w * w.w;
    }
    __syncthreads();
  }

  float4 b = *(const float4*)&bl2[j0];
#pragma unroll
  for (int i = 0; i < 4; i++) {
    int node = nbase + n0 + i;
    if (node < N) {
      float inv = 1.0f / fmaxf((float)deg[node], 1.0f);
      float4 ag = load4f(agg16 + (size_t)node * 64 + j0);
      acc[i].x += ag.x * inv + b.x;
      acc[i].y += ag.y * inv + b.y;
      acc[i].z += ag.z * inv + b.z;
      acc[i].w += ag.w * inv + b.w;
      *(uint2*)(h2 + (size_t)node * 64 + j0) = pack4(acc[i]);
    }
  }
}

// ---------------- edge MLP via f16 MFMA, original edge order ----------------
__global__ __launch_bounds__(256) void k_edge_mfma(
    const _Float16* __restrict__ h2, const int* __restrict__ src,
    const int* __restrict__ dst,
    const float* __restrict__ W1, const float* __restrict__ W2,
    const float* __restrict__ b1, const float* __restrict__ b2,
    float* __restrict__ out, int E) {
  const int gtid = blockIdx.x * blockDim.x + threadIdx.x;
  const int wave = gtid >> 6;
  const int nwaves = (gridDim.x * blockDim.x) >> 6;
  const int l = threadIdx.x & 63;
  const int col = l & 15;
  const int kb = (l >> 4) * 8;
  const int ngroups = (E + 15) / 16;
  const int gpw = (ngroups + nwaves - 1) / nwaves;
  const int g0 = wave * gpw;
  const int g1 = min(g0 + gpw, ngroups);
  if (g0 >= ngroups) return;

  f16x8 bfrag[8][2];
#pragma unroll
  for (int tt = 0; tt < 8; tt++)
#pragma unroll
    for (int s = 0; s < 2; s++) {
      f16x8 bf;
#pragma unroll
      for (int e = 0; e < 8; e++)
        bf[e] = (_Float16)W1[(size_t)(s * 32 + kb + e) * 128 + tt * 16 + col];
      bfrag[tt][s] = bf;
    }
  float b1r[8], w2r[8];
#pragma unroll
  for (int tt = 0; tt < 8; tt++) {
    b1r[tt] = b1[tt * 16 + col];
    w2r[tt] = W2[tt * 16 + col];
  }
  const float b2v = b2[0];

  auto ldrows = [&](int g, f16x8& a0, f16x8& a1) {
    int pos = g * 16 + col;
    if (pos >= E) pos = E - 1;
    int sp = src[pos], dp = dst[pos];
    f16x8 as0 = *(const f16x8*)(h2 + (size_t)sp * 64 + kb);
    f16x8 ad0 = *(const f16x8*)(h2 + (size_t)dp * 64 + kb);
    f16x8 as1 = *(const f16x8*)(h2 + (size_t)sp * 64 + 32 + kb);
    f16x8 ad1 = *(const f16x8*)(h2 + (size_t)dp * 64 + 32 + kb);
    a0 = as0 * ad0;
    a1 = as1 * ad1;
  };

  auto compute = [&](int g, f16x8 a0, f16x8 a1) {
    float p0 = 0.f, p1 = 0.f, p2 = 0.f, p3 = 0.f;
#pragma unroll
    for (int tt = 0; tt < 8; tt++) {
      f32x4 acc = {0.f, 0.f, 0.f, 0.f};
      acc = __builtin_amdgcn_mfma_f32_16x16x32_f16(a0, bfrag[tt][0], acc, 0, 0, 0);
      acc = __builtin_amdgcn_mfma_f32_16x16x32_f16(a1, bfrag[tt][1], acc, 0, 0, 0);
      p0 += fmaxf(acc[0] + b1r[tt], 0.f) * w2r[tt];
      p1 += fmaxf(acc[1] + b1r[tt], 0.f) * w2r[tt];
      p2 += fmaxf(acc[2] + b1r[tt], 0.f) * w2r[tt];
      p3 += fmaxf(acc[3] + b1r[tt], 0.f) * w2r[tt];
    }
#pragma unroll
    for (int m = 1; m < 16; m <<= 1) {
      p0 += __shfl_xor(p0, m, 64);
      p1 += __shfl_xor(p1, m, 64);
      p2 += __shfl_xor(p2, m, 64);
      p3 += __shfl_xor(p3, m, 64);
    }
    if (col == 0) {
      int ebase = g * 16 + (l >> 4) * 4;
      float pv[4] = {p0, p1, p2, p3};
#pragma unroll
      for (int r = 0; r < 4; r++) {
        int ep = ebase + r;
        if (ep < E) out[ep] = pv[r] + b2v;
      }
    }
  };

  f16x8 a0, a1, na0, na1;
  ldrows(g0, a0, a1);
  for (int g = g0; g < g1; g++) {
    if (g + 1 < g1) ldrows(g + 1, na0, na1);
    compute(g, a0, a1);
    a0 = na0; a1 = na1;
  }
}

// ---------------- launch ----------------
extern "C" void kernel_launch(void* const* d_in, const int* in_sizes, int n_in,
                              void* d_out, int out_size, void* d_ws, size_t ws_size,
                              hipStream_t stream) {
  const float* x   = (const float*)d_in[0];
  const int*   ei  = (const int*)d_in[1];
  const float* Wl1 = (const float*)d_in[2];
  const float* bl1 = (const float*)d_in[3];
  const float* Wr1 = (const float*)d_in[4];
  const float* Wl2 = (const float*)d_in[5];
  const float* bl2 = (const float*)d_in[6];
  const float* Wr2 = (const float*)d_in[7];
  const float* W1  = (const float*)d_in[8];
  const float* b1  = (const float*)d_in[9];
  const float* W2  = (const float*)d_in[10];
  const float* b2  = (const float*)d_in[11];
  const int N = in_sizes[0] / 64;
  const int E = in_sizes[1] / 2;
  const int* src = ei;
  const int* dstp = ei + E;

  char* w = (char*)d_ws;
  size_t off = 0;
  auto alloc = [&](size_t bytes) -> void* {
    void* p = w + off;
    off = (off + bytes + 255) & ~(size_t)255;
    return p;
  };
  int*      deg    = (int*)alloc((size_t)N * 4);
  int*      row    = (int*)alloc((size_t)(N + 1) * 4);
  int*      cursor = (int*)alloc((size_t)N * 4);
  int*      bsum   = (int*)alloc(1024 * 4);
  int*      srcs   = (int*)alloc((size_t)E * 4);
  _Float16* f16buf = (_Float16*)alloc((size_t)N * 64 * 2);   // x16 -> g16 -> h2
  _Float16* agg16  = (_Float16*)alloc((size_t)N * 64 * 2);   // aggX -> aggG
  _Float16* h1_16  = (_Float16*)alloc((size_t)N * 128 * 2);

  hipMemsetAsync(deg, 0, (size_t)N * 4, stream);
  int n4 = N * 16;
  int kag = (max(n4, E) + 255) / 256;
  kA_convert_hist<<<kag, 256, 0, stream>>>(x, f16buf, dstp, deg, n4, E);
  int nb = (N + 255) / 256;
  k_scan1<<<nb, 256, 0, stream>>>(deg, cursor, bsum, N);
  k_scan2<<<1, 1024, 0, stream>>>(bsum, nb);
  k_scan3<<<nb, 256, 0, stream>>>(bsum, row, cursor, N, E);
  k_bucket<<<(E + 255) / 256, 256, 0, stream>>>(src, dstp, cursor, srcs, E);

  int ngrid = (N + 63) / 64;
  int ggrid = (N * 16 + 255) / 256;
  k_gather16<<<ggrid, 256, 0, stream>>>(f16buf, row, srcs, agg16, N);
  k_h1_fused<<<ngrid, 256, 0, stream>>>(agg16, x, deg, Wl1, Wr1, bl1, Wl2,
                                        h1_16, f16buf, N);
  k_gather16<<<ggrid, 256, 0, stream>>>(f16buf, row, srcs, agg16, N);
  k_h2<<<ngrid, 256, 0, stream>>>(h1_16, agg16, deg, Wr2, bl2, f16buf, N);
  k_edge_mfma<<<4096, 256, 0, stream>>>(f16buf, src, dstp, W1, W2, b1, b2,
                                        (float*)d_out, E);
}

// Round 6
// 398.688 us; speedup vs baseline: 1.0870x; 1.0870x over previous
//
#include <hip/hip_runtime.h>

// GraphSAGE link predictor. f16 intermediates, 2-pass CSR bucket, f16-MFMA edge MLP.
// Pipeline:
//  kA: x16 = f16(x) + deg hist (fused)
//  scan -> row ; cbinit ; k_coarse (LDS-hist bucket by dst>>8, packed u64)
//  k_fine (clustered scatter -> srcs CSR)
//  agg16 = f16(segsum(x16[src]))            (gather, f32 accum)
//  h1 = (agg*inv)@Wl1 + x16@Wr1 + bl1       (tiled GEMM MODE0, f16 out)
//  g16 = h1@Wl2                             (tiled GEMM MODE1, f16 out)
//  agg16 = f16(segsum(g16[src]))            (gather)
//  h2 = h1@Wr2 + agg*inv + bl2              (tiled GEMM MODE2, f16 out)
//  out[e] = relu((h2[s]*h2[d])@W1+b1)@W2+b2 (MFMA f16, original edge order)

typedef _Float16 f16x8 __attribute__((ext_vector_type(8)));
typedef float f32x4 __attribute__((ext_vector_type(4)));

union H4 { _Float16 h[4]; uint2 u; };

__device__ inline float4 load4f(const _Float16* p) {
  H4 h; h.u = *(const uint2*)p;
  return make_float4((float)h.h[0], (float)h.h[1], (float)h.h[2], (float)h.h[3]);
}
__device__ inline uint2 pack4(float4 v) {
  H4 p;
  p.h[0] = (_Float16)v.x; p.h[1] = (_Float16)v.y;
  p.h[2] = (_Float16)v.z; p.h[3] = (_Float16)v.w;
  return p.u;
}

// ---------------- kA: f32->f16 convert + deg histogram ----------------
__global__ void kA_convert_hist(const float* __restrict__ x, _Float16* __restrict__ x16,
                                const int* __restrict__ dst, int* __restrict__ deg,
                                int n4, int E) {
  int t = blockIdx.x * blockDim.x + threadIdx.x;
  if (t < n4) {
    float4 v = ((const float4*)x)[t];
    ((uint2*)x16)[t] = pack4(v);
  }
  if (t < E) atomicAdd(&deg[dst[t]], 1);
}

// ---------------- scans ----------------
__global__ void k_scan1(const int* __restrict__ deg, int* __restrict__ ex,
                        int* __restrict__ bsum, int N) {
  __shared__ int sm[256];
  int t = threadIdx.x, i = blockIdx.x * 256 + t;
  int v = (i < N) ? deg[i] : 0;
  sm[t] = v;
  __syncthreads();
  for (int s = 1; s < 256; s <<= 1) {
    int a = (t >= s) ? sm[t - s] : 0;
    __syncthreads();
    sm[t] += a;
    __syncthreads();
  }
  if (i < N) ex[i] = sm[t] - v;
  if (t == 255) bsum[blockIdx.x] = sm[255];
}

__global__ void k_scan2(int* __restrict__ bsum, int nb) {
  __shared__ int sm[1024];
  int t = threadIdx.x;
  int v = (t < nb) ? bsum[t] : 0;
  sm[t] = v;
  __syncthreads();
  for (int s = 1; s < 1024; s <<= 1) {
    int a = (t >= s) ? sm[t - s] : 0;
    __syncthreads();
    sm[t] += a;
    __syncthreads();
  }
  if (t < nb) bsum[t] = sm[t] - v;
}

__global__ void k_scan3(const int* __restrict__ bsum, int* __restrict__ row,
                        int* __restrict__ cursor, int N, int E) {
  int i = blockIdx.x * blockDim.x + threadIdx.x;
  if (i < N) {
    int v = cursor[i] + bsum[i >> 8];
    row[i] = v;
    cursor[i] = v;
  }
  if (i == 0) row[N] = E;
}

// ---------------- coarse buckets: base = row[b<<8] ----------------
__global__ void k_cbinit(const int* __restrict__ row, int* __restrict__ cbcursor,
                         int N, int ncb) {
  int b = threadIdx.x + blockIdx.x * blockDim.x;
  if (b < ncb) {
    int node = b << 8;
    cbcursor[b] = row[node < N ? node : N];
  }
}

// ---------------- pass A: bucket edges by dst>>8 into packed u64 streams ----------
__global__ __launch_bounds__(256) void k_coarse(
    const int* __restrict__ src, const int* __restrict__ dst,
    int* __restrict__ cbcursor, unsigned long long* __restrict__ ep, int E) {
  __shared__ int lh[512];
  const int t = threadIdx.x;
  const int chunk = (E + gridDim.x - 1) / gridDim.x;
  const int e0 = blockIdx.x * chunk;
  const int e1 = min(e0 + chunk, E);
  lh[t] = 0; lh[t + 256] = 0;
  __syncthreads();
  for (int e = e0 + t; e < e1; e += 256)
    atomicAdd(&lh[dst[e] >> 8], 1);
  __syncthreads();
  {
    int c0 = lh[t], c1 = lh[t + 256];
    int b0 = c0 ? atomicAdd(&cbcursor[t], c0) : 0;
    int b1 = c1 ? atomicAdd(&cbcursor[t + 256], c1) : 0;
    __syncthreads();
    lh[t] = b0; lh[t + 256] = b1;
  }
  __syncthreads();
  for (int e = e0 + t; e < e1; e += 256) {
    int d = dst[e];
    int pos = atomicAdd(&lh[d >> 8], 1);
    ep[pos] = ((unsigned long long)d << 32) | (unsigned)src[e];
  }
}

// ---------------- pass B: clustered scatter into CSR srcs ----------------
__global__ __launch_bounds__(256) void k_fine(
    const unsigned long long* __restrict__ ep, int* __restrict__ cursor,
    int* __restrict__ srcs, int E) {
  int e = blockIdx.x * blockDim.x + threadIdx.x;
  if (e < E) {
    unsigned long long p = ep[e];
    int d = (int)(p >> 32), s = (int)(unsigned)p;
    int pos = atomicAdd(&cursor[d], 1);
    __builtin_nontemporal_store(s, &srcs[pos]);
  }
}

// ---------------- aggregation: 16 lanes/row, unroll 4, f16 out ----------------
__global__ __launch_bounds__(256) void k_gather16(
    const _Float16* __restrict__ feat, const int* __restrict__ row,
    const int* __restrict__ srcs, _Float16* __restrict__ agg, int N) {
  int tid = blockIdx.x * blockDim.x + threadIdx.x;
  int node = tid >> 4, slot = tid & 15;
  if (node >= N) return;
  int beg = row[node], end = row[node + 1];
  float4 acc = make_float4(0.f, 0.f, 0.f, 0.f);
  int k = beg;
  for (; k + 3 < end; k += 4) {
    int s0 = srcs[k], s1 = srcs[k + 1], s2 = srcs[k + 2], s3 = srcs[k + 3];
    H4 a, b, c, d;
    a.u = *(const uint2*)(feat + (size_t)s0 * 64 + slot * 4);
    b.u = *(const uint2*)(feat + (size_t)s1 * 64 + slot * 4);
    c.u = *(const uint2*)(feat + (size_t)s2 * 64 + slot * 4);
    d.u = *(const uint2*)(feat + (size_t)s3 * 64 + slot * 4);
    acc.x += ((float)a.h[0] + (float)b.h[0]) + ((float)c.h[0] + (float)d.h[0]);
    acc.y += ((float)a.h[1] + (float)b.h[1]) + ((float)c.h[1] + (float)d.h[1]);
    acc.z += ((float)a.h[2] + (float)b.h[2]) + ((float)c.h[2] + (float)d.h[2]);
    acc.w += ((float)a.h[3] + (float)b.h[3]) + ((float)c.h[3] + (float)d.h[3]);
  }
  for (; k < end; k++) {
    int s0 = srcs[k];
    H4 a; a.u = *(const uint2*)(feat + (size_t)s0 * 64 + slot * 4);
    acc.x += (float)a.h[0]; acc.y += (float)a.h[1];
    acc.z += (float)a.h[2]; acc.w += (float)a.h[3];
  }
  *(uint2*)(agg + (size_t)node * 64 + slot * 4) = pack4(acc);
}

// ---------------- tiled node GEMM (f16 in, f16 out): out[N][J] ----------------
// MODE 0 (h1): acc = A@W ; *= inv ; += A2@Wb ; += bias
// MODE 1 (g):  acc = A@W
// MODE 2 (h2): acc = A@W ; += add64*inv + bias
template <int K, int J, int MODE>
__global__ __launch_bounds__(256) void k_node_gemm16(
    const _Float16* __restrict__ A, const _Float16* __restrict__ A2,
    const float* __restrict__ W, const float* __restrict__ Wb,
    const float* __restrict__ bias, const _Float16* __restrict__ add64,
    const int* __restrict__ deg, _Float16* __restrict__ outp, int N) {
  constexpr int JT = J / 4;
  constexpr int NT = 256 / JT;
  constexpr int NPT = 64 / NT;
  constexpr int BK = 16;
  __shared__ float At[BK][64];
  __shared__ float Wt[BK][J];

  const int t = threadIdx.x;
  const int jt = t % JT, nt = t / JT;
  const int j0 = jt * 4, n0 = nt * NPT;
  const int nbase = blockIdx.x * 64;

  float4 acc[NPT];
#pragma unroll
  for (int r = 0; r < NPT; r++) acc[r] = make_float4(0.f, 0.f, 0.f, 0.f);

  auto phase = [&](const _Float16* __restrict__ S, const float* __restrict__ Wm) {
    for (int kb = 0; kb < K; kb += BK) {
      {
        int n = t >> 2, kq = t & 3;
        int node = nbase + n;
        int nclamp = node < N ? node : N - 1;
        float4 v = load4f(S + (size_t)nclamp * K + kb + kq * 4);
        At[kq * 4 + 0][n] = v.x;
        At[kq * 4 + 1][n] = v.y;
        At[kq * 4 + 2][n] = v.z;
        At[kq * 4 + 3][n] = v.w;
      }
      {
        const float* wsrc = Wm + (size_t)kb * J;
        float* wdst = &Wt[0][0];
#pragma unroll
        for (int p = 0; p < (BK * J) / (256 * 4); p++) {
          int idx = (t + p * 256) * 4;
          *(float4*)(wdst + idx) = *(const float4*)(wsrc + idx);
        }
      }
      __syncthreads();
#pragma unroll
      for (int kk = 0; kk < BK; kk++) {
        float4 w = *(const float4*)&Wt[kk][j0];
        float av[NPT];
#pragma unroll
        for (int rq = 0; rq < NPT / 4; rq++) {
          float4 a = *(const float4*)&At[kk][n0 + rq * 4];
          av[rq * 4 + 0] = a.x;
          av[rq * 4 + 1] = a.y;
          av[rq * 4 + 2] = a.z;
          av[rq * 4 + 3] = a.w;
        }
#pragma unroll
        for (int r = 0; r < NPT; r++) {
          acc[r].x += av[r] * w.x;
          acc[r].y += av[r] * w.y;
          acc[r].z += av[r] * w.z;
          acc[r].w += av[r] * w.w;
        }
      }
      __syncthreads();
    }
  };

  phase(A, W);

  if constexpr (MODE == 0) {
#pragma unroll
    for (int r = 0; r < NPT; r++) {
      int node = nbase + n0 + r;
      float inv = (node < N) ? 1.0f / fmaxf((float)deg[node], 1.0f) : 1.f;
      acc[r].x *= inv; acc[r].y *= inv; acc[r].z *= inv; acc[r].w *= inv;
    }
    phase(A2, Wb);
    float4 b = *(const float4*)&bias[j0];
#pragma unroll
    for (int r = 0; r < NPT; r++) {
      acc[r].x += b.x; acc[r].y += b.y; acc[r].z += b.z; acc[r].w += b.w;
    }
  }
  if constexpr (MODE == 2) {
    float4 b = *(const float4*)&bias[j0];
#pragma unroll
    for (int r = 0; r < NPT; r++) {
      int node = nbase + n0 + r;
      if (node < N) {
        float inv = 1.0f / fmaxf((float)deg[node], 1.0f);
        float4 ad = load4f(add64 + (size_t)node * J + j0);
        acc[r].x += ad.x * inv + b.x;
        acc[r].y += ad.y * inv + b.y;
        acc[r].z += ad.z * inv + b.z;
        acc[r].w += ad.w * inv + b.w;
      }
    }
  }

#pragma unroll
  for (int r = 0; r < NPT; r++) {
    int node = nbase + n0 + r;
    if (node < N)
      *(uint2*)(outp + (size_t)node * J + j0) = pack4(acc[r]);
  }
}

// ---------------- edge MLP via f16 MFMA, original edge order ----------------
__global__ __launch_bounds__(256) void k_edge_mfma(
    const _Float16* __restrict__ h2, const int* __restrict__ src,
    const int* __restrict__ dst,
    const float* __restrict__ W1, const float* __restrict__ W2,
    const float* __restrict__ b1, const float* __restrict__ b2,
    float* __restrict__ out, int E) {
  const int gtid = blockIdx.x * blockDim.x + threadIdx.x;
  const int wave = gtid >> 6;
  const int nwaves = (gridDim.x * blockDim.x) >> 6;
  const int l = threadIdx.x & 63;
  const int col = l & 15;
  const int kb = (l >> 4) * 8;
  const int ngroups = (E + 15) / 16;
  const int gpw = (ngroups + nwaves - 1) / nwaves;
  const int g0 = wave * gpw;
  const int g1 = min(g0 + gpw, ngroups);
  if (g0 >= ngroups) return;

  f16x8 bfrag[8][2];
#pragma unroll
  for (int tt = 0; tt < 8; tt++)
#pragma unroll
    for (int s = 0; s < 2; s++) {
      f16x8 bf;
#pragma unroll
      for (int e = 0; e < 8; e++)
        bf[e] = (_Float16)W1[(size_t)(s * 32 + kb + e) * 128 + tt * 16 + col];
      bfrag[tt][s] = bf;
    }
  float b1r[8], w2r[8];
#pragma unroll
  for (int tt = 0; tt < 8; tt++) {
    b1r[tt] = b1[tt * 16 + col];
    w2r[tt] = W2[tt * 16 + col];
  }
  const float b2v = b2[0];

  auto ldrows = [&](int g, f16x8& a0, f16x8& a1) {
    int pos = g * 16 + col;
    if (pos >= E) pos = E - 1;
    int sp = src[pos], dp = dst[pos];
    f16x8 as0 = *(const f16x8*)(h2 + (size_t)sp * 64 + kb);
    f16x8 ad0 = *(const f16x8*)(h2 + (size_t)dp * 64 + kb);
    f16x8 as1 = *(const f16x8*)(h2 + (size_t)sp * 64 + 32 + kb);
    f16x8 ad1 = *(const f16x8*)(h2 + (size_t)dp * 64 + 32 + kb);
    a0 = as0 * ad0;
    a1 = as1 * ad1;
  };

  auto compute = [&](int g, f16x8 a0, f16x8 a1) {
    float p0 = 0.f, p1 = 0.f, p2 = 0.f, p3 = 0.f;
#pragma unroll
    for (int tt = 0; tt < 8; tt++) {
      f32x4 acc = {0.f, 0.f, 0.f, 0.f};
      acc = __builtin_amdgcn_mfma_f32_16x16x32_f16(a0, bfrag[tt][0], acc, 0, 0, 0);
      acc = __builtin_amdgcn_mfma_f32_16x16x32_f16(a1, bfrag[tt][1], acc, 0, 0, 0);
      p0 += fmaxf(acc[0] + b1r[tt], 0.f) * w2r[tt];
      p1 += fmaxf(acc[1] + b1r[tt], 0.f) * w2r[tt];
      p2 += fmaxf(acc[2] + b1r[tt], 0.f) * w2r[tt];
      p3 += fmaxf(acc[3] + b1r[tt], 0.f) * w2r[tt];
    }
#pragma unroll
    for (int m = 1; m < 16; m <<= 1) {
      p0 += __shfl_xor(p0, m, 64);
      p1 += __shfl_xor(p1, m, 64);
      p2 += __shfl_xor(p2, m, 64);
      p3 += __shfl_xor(p3, m, 64);
    }
    if (col == 0) {
      int ebase = g * 16 + (l >> 4) * 4;
      float pv[4] = {p0, p1, p2, p3};
#pragma unroll
      for (int r = 0; r < 4; r++) {
        int ep = ebase + r;
        if (ep < E) out[ep] = pv[r] + b2v;
      }
    }
  };

  f16x8 a0, a1, na0, na1;
  ldrows(g0, a0, a1);
  for (int g = g0; g < g1; g++) {
    if (g + 1 < g1) ldrows(g + 1, na0, na1);
    compute(g, a0, a1);
    a0 = na0; a1 = na1;
  }
}

// ---------------- launch ----------------
extern "C" void kernel_launch(void* const* d_in, const int* in_sizes, int n_in,
                              void* d_out, int out_size, void* d_ws, size_t ws_size,
                              hipStream_t stream) {
  const float* x   = (const float*)d_in[0];
  const int*   ei  = (const int*)d_in[1];
  const float* Wl1 = (const float*)d_in[2];
  const float* bl1 = (const float*)d_in[3];
  const float* Wr1 = (const float*)d_in[4];
  const float* Wl2 = (const float*)d_in[5];
  const float* bl2 = (const float*)d_in[6];
  const float* Wr2 = (const float*)d_in[7];
  const float* W1  = (const float*)d_in[8];
  const float* b1  = (const float*)d_in[9];
  const float* W2  = (const float*)d_in[10];
  const float* b2  = (const float*)d_in[11];
  const int N = in_sizes[0] / 64;
  const int E = in_sizes[1] / 2;
  const int* src = ei;
  const int* dstp = ei + E;

  char* w = (char*)d_ws;
  size_t off = 0;
  auto alloc = [&](size_t bytes) -> void* {
    void* p = w + off;
    off = (off + bytes + 255) & ~(size_t)255;
    return p;
  };
  int*      deg      = (int*)alloc((size_t)N * 4);
  int*      row      = (int*)alloc((size_t)(N + 1) * 4);
  int*      cursor   = (int*)alloc((size_t)N * 4);
  int*      bsum     = (int*)alloc(1024 * 4);
  int*      cbcursor = (int*)alloc(512 * 4);
  int*      srcs     = (int*)alloc((size_t)E * 4);
  unsigned long long* ep = (unsigned long long*)alloc((size_t)E * 8);
  _Float16* f16buf   = (_Float16*)alloc((size_t)N * 64 * 2);   // x16 -> g16 -> h2
  _Float16* agg16    = (_Float16*)alloc((size_t)N * 64 * 2);   // aggX -> aggG
  _Float16* h1_16    = (_Float16*)alloc((size_t)N * 128 * 2);

  const int ncb = (N + 255) >> 8;

  hipMemsetAsync(deg, 0, (size_t)N * 4, stream);
  int n4 = N * 16;
  int kag = (max(n4, E) + 255) / 256;
  kA_convert_hist<<<kag, 256, 0, stream>>>(x, f16buf, dstp, deg, n4, E);
  int nb = (N + 255) / 256;
  k_scan1<<<nb, 256, 0, stream>>>(deg, cursor, bsum, N);
  k_scan2<<<1, 1024, 0, stream>>>(bsum, nb);
  k_scan3<<<nb, 256, 0, stream>>>(bsum, row, cursor, N, E);
  k_cbinit<<<2, 256, 0, stream>>>(row, cbcursor, N, ncb);
  k_coarse<<<256, 256, 0, stream>>>(src, dstp, cbcursor, ep, E);
  k_fine<<<(E + 255) / 256, 256, 0, stream>>>(ep, cursor, srcs, E);

  int ngrid = (N + 63) / 64;
  int ggrid = (N * 16 + 255) / 256;
  k_gather16<<<ggrid, 256, 0, stream>>>(f16buf, row, srcs, agg16, N);
  k_node_gemm16<64, 128, 0><<<ngrid, 256, 0, stream>>>(
      agg16, f16buf, Wl1, Wr1, bl1, nullptr, deg, h1_16, N);
  k_node_gemm16<128, 64, 1><<<ngrid, 256, 0, stream>>>(
      h1_16, nullptr, Wl2, nullptr, nullptr, nullptr, nullptr, f16buf, N);
  k_gather16<<<ggrid, 256, 0, stream>>>(f16buf, row, srcs, agg16, N);
  k_node_gemm16<128, 64, 2><<<ngrid, 256, 0, stream>>>(
      h1_16, nullptr, Wr2, nullptr, bl2, agg16, deg, f16buf, N);
  k_edge_mfma<<<8192, 256, 0, stream>>>(f16buf, src, dstp, W1, W2, b1, b2,
                                        (float*)d_out, E);
}

// Round 7
// 355.802 us; speedup vs baseline: 1.2180x; 1.1205x over previous
//
#include <hip/hip_runtime.h>

// GraphSAGE link predictor. f16 intermediates, 2-pass CSR bucket (LDS sort), f16-MFMA edge MLP.
// Pipeline:
//  kA: x16 = f16(x) + deg hist (fused)
//  scan -> row ; cbinit ; k_coarse (LDS-hist bucket by dst>>8, packed u64)
//  k_fine_sort (per-bucket LDS count-sort -> coalesced srcs CSR write)
//  agg16 = f16(segsum(x16[src]))            (gather, f32 accum)
//  h1 = (agg*inv)@Wl1 + x16@Wr1 + bl1       (tiled GEMM MODE0, f16 out)
//  g16 = h1@Wl2                             (tiled GEMM MODE1, f16 out)
//  agg16 = f16(segsum(g16[src]))            (gather)
//  h2 = h1@Wr2 + agg*inv + bl2              (tiled GEMM MODE2, f16 out)
//  out[e] = relu((h2[s]*h2[d])@W1+b1)@W2+b2 (MFMA f16, original edge order, 4096 blocks)

typedef _Float16 f16x8 __attribute__((ext_vector_type(8)));
typedef float f32x4 __attribute__((ext_vector_type(4)));

union H4 { _Float16 h[4]; uint2 u; };

__device__ inline float4 load4f(const _Float16* p) {
  H4 h; h.u = *(const uint2*)p;
  return make_float4((float)h.h[0], (float)h.h[1], (float)h.h[2], (float)h.h[3]);
}
__device__ inline uint2 pack4(float4 v) {
  H4 p;
  p.h[0] = (_Float16)v.x; p.h[1] = (_Float16)v.y;
  p.h[2] = (_Float16)v.z; p.h[3] = (_Float16)v.w;
  return p.u;
}

// ---------------- kA: f32->f16 convert + deg histogram ----------------
__global__ void kA_convert_hist(const float* __restrict__ x, _Float16* __restrict__ x16,
                                const int* __restrict__ dst, int* __restrict__ deg,
                                int n4, int E) {
  int t = blockIdx.x * blockDim.x + threadIdx.x;
  if (t < n4) {
    float4 v = ((const float4*)x)[t];
    ((uint2*)x16)[t] = pack4(v);
  }
  if (t < E) atomicAdd(&deg[dst[t]], 1);
}

// ---------------- scans ----------------
__global__ void k_scan1(const int* __restrict__ deg, int* __restrict__ ex,
                        int* __restrict__ bsum, int N) {
  __shared__ int sm[256];
  int t = threadIdx.x, i = blockIdx.x * 256 + t;
  int v = (i < N) ? deg[i] : 0;
  sm[t] = v;
  __syncthreads();
  for (int s = 1; s < 256; s <<= 1) {
    int a = (t >= s) ? sm[t - s] : 0;
    __syncthreads();
    sm[t] += a;
    __syncthreads();
  }
  if (i < N) ex[i] = sm[t] - v;
  if (t == 255) bsum[blockIdx.x] = sm[255];
}

__global__ void k_scan2(int* __restrict__ bsum, int nb) {
  __shared__ int sm[1024];
  int t = threadIdx.x;
  int v = (t < nb) ? bsum[t] : 0;
  sm[t] = v;
  __syncthreads();
  for (int s = 1; s < 1024; s <<= 1) {
    int a = (t >= s) ? sm[t - s] : 0;
    __syncthreads();
    sm[t] += a;
    __syncthreads();
  }
  if (t < nb) bsum[t] = sm[t] - v;
}

__global__ void k_scan3(const int* __restrict__ bsum, int* __restrict__ row,
                        const int* __restrict__ ex, int N, int E) {
  int i = blockIdx.x * blockDim.x + threadIdx.x;
  if (i < N) row[i] = ex[i] + bsum[i >> 8];
  if (i == 0) row[N] = E;
}

// ---------------- coarse buckets: base = row[b<<8] ----------------
__global__ void k_cbinit(const int* __restrict__ row, int* __restrict__ cbcursor,
                         int N, int ncb) {
  int b = threadIdx.x + blockIdx.x * blockDim.x;
  if (b < ncb) {
    int node = b << 8;
    cbcursor[b] = row[node < N ? node : N];
  }
}

// ---------------- pass A: bucket edges by dst>>8 into packed u64 streams ----------
__global__ __launch_bounds__(256) void k_coarse(
    const int* __restrict__ src, const int* __restrict__ dst,
    int* __restrict__ cbcursor, unsigned long long* __restrict__ ep, int E) {
  __shared__ int lh[512];
  const int t = threadIdx.x;
  const int chunk = (E + gridDim.x - 1) / gridDim.x;
  const int e0 = blockIdx.x * chunk;
  const int e1 = min(e0 + chunk, E);
  lh[t] = 0; lh[t + 256] = 0;
  __syncthreads();
  for (int e = e0 + t; e < e1; e += 256)
    atomicAdd(&lh[dst[e] >> 8], 1);
  __syncthreads();
  {
    int c0 = lh[t], c1 = lh[t + 256];
    int b0 = c0 ? atomicAdd(&cbcursor[t], c0) : 0;
    int b1 = c1 ? atomicAdd(&cbcursor[t + 256], c1) : 0;
    __syncthreads();
    lh[t] = b0; lh[t + 256] = b1;
  }
  __syncthreads();
  for (int e = e0 + t; e < e1; e += 256) {
    int d = dst[e];
    int pos = atomicAdd(&lh[d >> 8], 1);
    ep[pos] = ((unsigned long long)d << 32) | (unsigned)src[e];
  }
}

// ---------------- pass B: per-bucket LDS count-sort -> coalesced srcs ----------
#define FS_CAP 4608
__global__ __launch_bounds__(256) void k_fine_sort(
    const unsigned long long* __restrict__ ep, const int* __restrict__ row,
    int* __restrict__ srcs, int N, int E) {
  __shared__ int cnt[256];
  __shared__ int cur[256];
  __shared__ int sm[256];
  __shared__ int stage[FS_CAP];
  const int b = blockIdx.x;
  const int t = threadIdx.x;
  const int n0 = b << 8;
  const int n1 = min(n0 + 256, N);
  const int beg = row[n0];
  const int end = row[n1];
  const int M = end - beg;

  cnt[t] = 0;
  __syncthreads();
  for (int i = beg + t; i < end; i += 256) {
    int loc = (int)(ep[i] >> 32) & 255;
    atomicAdd(&cnt[loc], 1);
  }
  __syncthreads();
  // exclusive scan of cnt
  int v = cnt[t];
  sm[t] = v;
  __syncthreads();
  for (int s = 1; s < 256; s <<= 1) {
    int a = (t >= s) ? sm[t - s] : 0;
    __syncthreads();
    sm[t] += a;
    __syncthreads();
  }
  cur[t] = sm[t] - v;
  __syncthreads();
  for (int i = beg + t; i < end; i += 256) {
    unsigned long long p = ep[i];
    int loc = (int)(p >> 32) & 255;
    int pos = atomicAdd(&cur[loc], 1);
    if (pos < FS_CAP) stage[pos] = (int)(unsigned)p;
    else srcs[beg + pos] = (int)(unsigned)p;   // statistically never
  }
  __syncthreads();
  const int m = min(M, FS_CAP);
  for (int i = t; i < m; i += 256) srcs[beg + i] = stage[i];
}

// ---------------- aggregation: 16 lanes/row, unroll 4, f16 out ----------------
__global__ __launch_bounds__(256) void k_gather16(
    const _Float16* __restrict__ feat, const int* __restrict__ row,
    const int* __restrict__ srcs, _Float16* __restrict__ agg, int N) {
  int tid = blockIdx.x * blockDim.x + threadIdx.x;
  int node = tid >> 4, slot = tid & 15;
  if (node >= N) return;
  int beg = row[node], end = row[node + 1];
  float4 acc = make_float4(0.f, 0.f, 0.f, 0.f);
  int k = beg;
  for (; k + 3 < end; k += 4) {
    int s0 = srcs[k], s1 = srcs[k + 1], s2 = srcs[k + 2], s3 = srcs[k + 3];
    H4 a, b, c, d;
    a.u = *(const uint2*)(feat + (size_t)s0 * 64 + slot * 4);
    b.u = *(const uint2*)(feat + (size_t)s1 * 64 + slot * 4);
    c.u = *(const uint2*)(feat + (size_t)s2 * 64 + slot * 4);
    d.u = *(const uint2*)(feat + (size_t)s3 * 64 + slot * 4);
    acc.x += ((float)a.h[0] + (float)b.h[0]) + ((float)c.h[0] + (float)d.h[0]);
    acc.y += ((float)a.h[1] + (float)b.h[1]) + ((float)c.h[1] + (float)d.h[1]);
    acc.z += ((float)a.h[2] + (float)b.h[2]) + ((float)c.h[2] + (float)d.h[2]);
    acc.w += ((float)a.h[3] + (float)b.h[3]) + ((float)c.h[3] + (float)d.h[3]);
  }
  for (; k < end; k++) {
    int s0 = srcs[k];
    H4 a; a.u = *(const uint2*)(feat + (size_t)s0 * 64 + slot * 4);
    acc.x += (float)a.h[0]; acc.y += (float)a.h[1];
    acc.z += (float)a.h[2]; acc.w += (float)a.h[3];
  }
  *(uint2*)(agg + (size_t)node * 64 + slot * 4) = pack4(acc);
}

// ---------------- tiled node GEMM (f16 in, f16 out): out[N][J] ----------------
template <int K, int J, int MODE>
__global__ __launch_bounds__(256) void k_node_gemm16(
    const _Float16* __restrict__ A, const _Float16* __restrict__ A2,
    const float* __restrict__ W, const float* __restrict__ Wb,
    const float* __restrict__ bias, const _Float16* __restrict__ add64,
    const int* __restrict__ deg, _Float16* __restrict__ outp, int N) {
  constexpr int JT = J / 4;
  constexpr int NT = 256 / JT;
  constexpr int NPT = 64 / NT;
  constexpr int BK = 16;
  __shared__ float At[BK][64];
  __shared__ float Wt[BK][J];

  const int t = threadIdx.x;
  const int jt = t % JT, nt = t / JT;
  const int j0 = jt * 4, n0 = nt * NPT;
  const int nbase = blockIdx.x * 64;

  float4 acc[NPT];
#pragma unroll
  for (int r = 0; r < NPT; r++) acc[r] = make_float4(0.f, 0.f, 0.f, 0.f);

  auto phase = [&](const _Float16* __restrict__ S, const float* __restrict__ Wm) {
    for (int kb = 0; kb < K; kb += BK) {
      {
        int n = t >> 2, kq = t & 3;
        int node = nbase + n;
        int nclamp = node < N ? node : N - 1;
        float4 v = load4f(S + (size_t)nclamp * K + kb + kq * 4);
        At[kq * 4 + 0][n] = v.x;
        At[kq * 4 + 1][n] = v.y;
        At[kq * 4 + 2][n] = v.z;
        At[kq * 4 + 3][n] = v.w;
      }
      {
        const float* wsrc = Wm + (size_t)kb * J;
        float* wdst = &Wt[0][0];
#pragma unroll
        for (int p = 0; p < (BK * J) / (256 * 4); p++) {
          int idx = (t + p * 256) * 4;
          *(float4*)(wdst + idx) = *(const float4*)(wsrc + idx);
        }
      }
      __syncthreads();
#pragma unroll
      for (int kk = 0; kk < BK; kk++) {
        float4 w = *(const float4*)&Wt[kk][j0];
        float av[NPT];
#pragma unroll
        for (int rq = 0; rq < NPT / 4; rq++) {
          float4 a = *(const float4*)&At[kk][n0 + rq * 4];
          av[rq * 4 + 0] = a.x;
          av[rq * 4 + 1] = a.y;
          av[rq * 4 + 2] = a.z;
          av[rq * 4 + 3] = a.w;
        }
#pragma unroll
        for (int r = 0; r < NPT; r++) {
          acc[r].x += av[r] * w.x;
          acc[r].y += av[r] * w.y;
          acc[r].z += av[r] * w.z;
          acc[r].w += av[r] * w.w;
        }
      }
      __syncthreads();
    }
  };

  phase(A, W);

  if constexpr (MODE == 0) {
#pragma unroll
    for (int r = 0; r < NPT; r++) {
      int node = nbase + n0 + r;
      float inv = (node < N) ? 1.0f / fmaxf((float)deg[node], 1.0f) : 1.f;
      acc[r].x *= inv; acc[r].y *= inv; acc[r].z *= inv; acc[r].w *= inv;
    }
    phase(A2, Wb);
    float4 b = *(const float4*)&bias[j0];
#pragma unroll
    for (int r = 0; r < NPT; r++) {
      acc[r].x += b.x; acc[r].y += b.y; acc[r].z += b.z; acc[r].w += b.w;
    }
  }
  if constexpr (MODE == 2) {
    float4 b = *(const float4*)&bias[j0];
#pragma unroll
    for (int r = 0; r < NPT; r++) {
      int node = nbase + n0 + r;
      if (node < N) {
        float inv = 1.0f / fmaxf((float)deg[node], 1.0f);
        float4 ad = load4f(add64 + (size_t)node * J + j0);
        acc[r].x += ad.x * inv + b.x;
        acc[r].y += ad.y * inv + b.y;
        acc[r].z += ad.z * inv + b.z;
        acc[r].w += ad.w * inv + b.w;
      }
    }
  }

#pragma unroll
  for (int r = 0; r < NPT; r++) {
    int node = nbase + n0 + r;
    if (node < N)
      *(uint2*)(outp + (size_t)node * J + j0) = pack4(acc[r]);
  }
}

// ---------------- edge MLP via f16 MFMA, original edge order ----------------
__global__ __launch_bounds__(256) void k_edge_mfma(
    const _Float16* __restrict__ h2, const int* __restrict__ src,
    const int* __restrict__ dst,
    const float* __restrict__ W1, const float* __restrict__ W2,
    const float* __restrict__ b1, const float* __restrict__ b2,
    float* __restrict__ out, int E) {
  const int gtid = blockIdx.x * blockDim.x + threadIdx.x;
  const int wave = gtid >> 6;
  const int nwaves = (gridDim.x * blockDim.x) >> 6;
  const int l = threadIdx.x & 63;
  const int col = l & 15;
  const int kb = (l >> 4) * 8;
  const int ngroups = (E + 15) / 16;
  const int gpw = (ngroups + nwaves - 1) / nwaves;
  const int g0 = wave * gpw;
  const int g1 = min(g0 + gpw, ngroups);
  if (g0 >= ngroups) return;

  f16x8 bfrag[8][2];
#pragma unroll
  for (int tt = 0; tt < 8; tt++)
#pragma unroll
    for (int s = 0; s < 2; s++) {
      f16x8 bf;
#pragma unroll
      for (int e = 0; e < 8; e++)
        bf[e] = (_Float16)W1[(size_t)(s * 32 + kb + e) * 128 + tt * 16 + col];
      bfrag[tt][s] = bf;
    }
  float b1r[8], w2r[8];
#pragma unroll
  for (int tt = 0; tt < 8; tt++) {
    b1r[tt] = b1[tt * 16 + col];
    w2r[tt] = W2[tt * 16 + col];
  }
  const float b2v = b2[0];

  auto ldrows = [&](int g, f16x8& a0, f16x8& a1) {
    int pos = g * 16 + col;
    if (pos >= E) pos = E - 1;
    int sp = src[pos], dp = dst[pos];
    f16x8 as0 = *(const f16x8*)(h2 + (size_t)sp * 64 + kb);
    f16x8 ad0 = *(const f16x8*)(h2 + (size_t)dp * 64 + kb);
    f16x8 as1 = *(const f16x8*)(h2 + (size_t)sp * 64 + 32 + kb);
    f16x8 ad1 = *(const f16x8*)(h2 + (size_t)dp * 64 + 32 + kb);
    a0 = as0 * ad0;
    a1 = as1 * ad1;
  };

  auto compute = [&](int g, f16x8 a0, f16x8 a1) {
    float p0 = 0.f, p1 = 0.f, p2 = 0.f, p3 = 0.f;
#pragma unroll
    for (int tt = 0; tt < 8; tt++) {
      f32x4 acc = {0.f, 0.f, 0.f, 0.f};
      acc = __builtin_amdgcn_mfma_f32_16x16x32_f16(a0, bfrag[tt][0], acc, 0, 0, 0);
      acc = __builtin_amdgcn_mfma_f32_16x16x32_f16(a1, bfrag[tt][1], acc, 0, 0, 0);
      p0 += fmaxf(acc[0] + b1r[tt], 0.f) * w2r[tt];
      p1 += fmaxf(acc[1] + b1r[tt], 0.f) * w2r[tt];
      p2 += fmaxf(acc[2] + b1r[tt], 0.f) * w2r[tt];
      p3 += fmaxf(acc[3] + b1r[tt], 0.f) * w2r[tt];
    }
#pragma unroll
    for (int m = 1; m < 16; m <<= 1) {
      p0 += __shfl_xor(p0, m, 64);
      p1 += __shfl_xor(p1, m, 64);
      p2 += __shfl_xor(p2, m, 64);
      p3 += __shfl_xor(p3, m, 64);
    }
    if (col == 0) {
      int ebase = g * 16 + (l >> 4) * 4;
      float pv[4] = {p0, p1, p2, p3};
#pragma unroll
      for (int r = 0; r < 4; r++) {
        int ep = ebase + r;
        if (ep < E) out[ep] = pv[r] + b2v;
      }
    }
  };

  f16x8 a0, a1, na0, na1;
  ldrows(g0, a0, a1);
  for (int g = g0; g < g1; g++) {
    if (g + 1 < g1) ldrows(g + 1, na0, na1);
    compute(g, a0, a1);
    a0 = na0; a1 = na1;
  }
}

// ---------------- launch ----------------
extern "C" void kernel_launch(void* const* d_in, const int* in_sizes, int n_in,
                              void* d_out, int out_size, void* d_ws, size_t ws_size,
                              hipStream_t stream) {
  const float* x   = (const float*)d_in[0];
  const int*   ei  = (const int*)d_in[1];
  const float* Wl1 = (const float*)d_in[2];
  const float* bl1 = (const float*)d_in[3];
  const float* Wr1 = (const float*)d_in[4];
  const float* Wl2 = (const float*)d_in[5];
  const float* bl2 = (const float*)d_in[6];
  const float* Wr2 = (const float*)d_in[7];
  const float* W1  = (const float*)d_in[8];
  const float* b1  = (const float*)d_in[9];
  const float* W2  = (const float*)d_in[10];
  const float* b2  = (const float*)d_in[11];
  const int N = in_sizes[0] / 64;
  const int E = in_sizes[1] / 2;
  const int* src = ei;
  const int* dstp = ei + E;

  char* w = (char*)d_ws;
  size_t off = 0;
  auto alloc = [&](size_t bytes) -> void* {
    void* p = w + off;
    off = (off + bytes + 255) & ~(size_t)255;
    return p;
  };
  int*      deg      = (int*)alloc((size_t)N * 4);
  int*      row      = (int*)alloc((size_t)(N + 1) * 4);
  int*      ex       = (int*)alloc((size_t)N * 4);
  int*      bsum     = (int*)alloc(1024 * 4);
  int*      cbcursor = (int*)alloc(512 * 4);
  int*      srcs     = (int*)alloc((size_t)E * 4);
  unsigned long long* ep = (unsigned long long*)alloc((size_t)E * 8);
  _Float16* f16buf   = (_Float16*)alloc((size_t)N * 64 * 2);   // x16 -> g16 -> h2
  _Float16* agg16    = (_Float16*)alloc((size_t)N * 64 * 2);   // aggX -> aggG
  _Float16* h1_16    = (_Float16*)alloc((size_t)N * 128 * 2);

  const int ncb = (N + 255) >> 8;

  hipMemsetAsync(deg, 0, (size_t)N * 4, stream);
  int n4 = N * 16;
  int kag = (max(n4, E) + 255) / 256;
  kA_convert_hist<<<kag, 256, 0, stream>>>(x, f16buf, dstp, deg, n4, E);
  int nb = (N + 255) / 256;
  k_scan1<<<nb, 256, 0, stream>>>(deg, ex, bsum, N);
  k_scan2<<<1, 1024, 0, stream>>>(bsum, nb);
  k_scan3<<<nb, 256, 0, stream>>>(bsum, row, ex, N, E);
  k_cbinit<<<2, 256, 0, stream>>>(row, cbcursor, N, ncb);
  k_coarse<<<256, 256, 0, stream>>>(src, dstp, cbcursor, ep, E);
  k_fine_sort<<<ncb, 256, 0, stream>>>(ep, row, srcs, N, E);

  int ngrid = (N + 63) / 64;
  int ggrid = (N * 16 + 255) / 256;
  k_gather16<<<ggrid, 256, 0, stream>>>(f16buf, row, srcs, agg16, N);
  k_node_gemm16<64, 128, 0><<<ngrid, 256, 0, stream>>>(
      agg16, f16buf, Wl1, Wr1, bl1, nullptr, deg, h1_16, N);
  k_node_gemm16<128, 64, 1><<<ngrid, 256, 0, stream>>>(
      h1_16, nullptr, Wl2, nullptr, nullptr, nullptr, nullptr, f16buf, N);
  k_gather16<<<ggrid, 256, 0, stream>>>(f16buf, row, srcs, agg16, N);
  k_node_gemm16<128, 64, 2><<<ngrid, 256, 0, stream>>>(
      h1_16, nullptr, Wr2, nullptr, bl2, agg16, deg, f16buf, N);
  k_edge_mfma<<<4096, 256, 0, stream>>>(f16buf, src, dstp, W1, W2, b1, b2,
                                        (float*)d_out, E);
}